// Round 1
// baseline (1617.203 us; speedup 1.0000x reference)
//
#include <hip/hip_runtime.h>
#include <hip/hip_bf16.h>
#include <math.h>
#include <stdint.h>

#define D_MODEL 2048
#define D_FF    8192
#define MTOK    16384   // 4 * 4096 tokens

typedef __bf16 bf16x8 __attribute__((ext_vector_type(8)));
typedef float  f32x4  __attribute__((ext_vector_type(4)));

// width-16 async global->LDS (per-lane global addr, wave-uniform LDS base + lane*16)
#define GLOAD_LDS16(gp, lp)                                                   \
  __builtin_amdgcn_global_load_lds(                                           \
      (__attribute__((address_space(1))) void*)(gp),                          \
      (__attribute__((address_space(3))) void*)(lp), 16, 0, 0)

// ---------------- sum(|w|) reduction ----------------
__global__ void absum_kernel(const float* __restrict__ w, int n4, float* __restrict__ out) {
    int tid = blockIdx.x * blockDim.x + threadIdx.x;
    int stride = gridDim.x * blockDim.x;
    float s = 0.f;
    for (int i = tid; i < n4; i += stride) {
        float4 v = ((const float4*)w)[i];
        s += fabsf(v.x) + fabsf(v.y) + fabsf(v.z) + fabsf(v.w);
    }
    #pragma unroll
    for (int off = 32; off > 0; off >>= 1) s += __shfl_down(s, off, 64);
    if ((threadIdx.x & 63) == 0) atomicAdd(out, s);
}

// ---------------- ternarize to bf16 {-1,0,+1} ----------------
__global__ void quant_kernel(const float* __restrict__ w, int n,
                             const float* __restrict__ sum, float inv_n,
                             __bf16* __restrict__ q) {
    int i = (blockIdx.x * blockDim.x + threadIdx.x) * 4;
    if (i >= n) return;
    float thr = 0.7f * (*sum) * inv_n;
    float4 v = *(const float4*)(w + i);
    __bf16 o0 = (__bf16)((fabsf(v.x) >= thr) ? (v.x > 0.f ? 1.f : -1.f) : 0.f);
    __bf16 o1 = (__bf16)((fabsf(v.y) >= thr) ? (v.y > 0.f ? 1.f : -1.f) : 0.f);
    __bf16 o2 = (__bf16)((fabsf(v.z) >= thr) ? (v.z > 0.f ? 1.f : -1.f) : 0.f);
    __bf16 o3 = (__bf16)((fabsf(v.w) >= thr) ? (v.w > 0.f ? 1.f : -1.f) : 0.f);
    q[i] = o0; q[i+1] = o1; q[i+2] = o2; q[i+3] = o3;
}

// ---------------- x fp32 -> bf16 ----------------
__global__ void cvt_kernel(const float* __restrict__ x, __bf16* __restrict__ xb, int n) {
    int i = (blockIdx.x * blockDim.x + threadIdx.x) * 4;
    if (i >= n) return;
    float4 v = *(const float4*)(x + i);
    xb[i] = (__bf16)v.x; xb[i+1] = (__bf16)v.y; xb[i+2] = (__bf16)v.z; xb[i+3] = (__bf16)v.w;
}

// ---------------- 128x128 bf16 MFMA GEMM, C = A[M,K] * B[N,K]^T ----------------
// EPI==0: out = bf16( gelu_exact(C + bias) )   (fc1)
// EPI==1: out = f32 ( C + bias )               (fc2)
// LDS tiles As/Bs [128 rows][64 k] bf16, row stride 128B. 16B chunk c within a
// row is stored at slot c ^ (row&7)  -> ds_read_b128 fragment reads become
// 2-way bank aliases (free) instead of 16-way.
template<int EPI>
__global__ __launch_bounds__(256) void gemm_bt(
    const __bf16* __restrict__ A,   // [M,K]
    const __bf16* __restrict__ B,   // [N,K]
    const float*  __restrict__ bias,// [N]
    void* __restrict__ Cout,
    int M, int N, int K)
{
    __shared__ __bf16 As[128 * 64];
    __shared__ __bf16 Bs[128 * 64];

    const int tid  = threadIdx.x;
    const int wave = tid >> 6;
    const int lane = tid & 63;
    const int m0 = blockIdx.y * 128;
    const int n0 = blockIdx.x * 128;
    const int wm = (wave >> 1) * 64;   // wave's m offset in tile
    const int wn = (wave & 1) * 64;    // wave's n offset in tile

    f32x4 acc[4][4] = {};

    const int quad = lane >> 4;
    const int l15  = lane & 15;

    const int nk = K >> 6;
    for (int kt = 0; kt < nk; ++kt) {
        const int k0 = kt << 6;
        // ---- stage A and B tiles: 1024 chunks of 16B each, 4 iters x 4 waves x 64 lanes
        #pragma unroll
        for (int it = 0; it < 4; ++it) {
            int slot = it * 256 + wave * 64 + lane;      // LDS 16B-slot index
            int row  = slot >> 3;
            int cg   = (slot & 7) ^ (row & 7);           // global 16B chunk in row (un-swizzle)
            const __bf16* ga = A + (size_t)(m0 + row) * K + k0 + cg * 8;
            const __bf16* gb = B + (size_t)(n0 + row) * K + k0 + cg * 8;
            char* la = (char*)As + (size_t)(it * 256 + wave * 64) * 16; // wave-uniform base
            char* lb = (char*)Bs + (size_t)(it * 256 + wave * 64) * 16;
            GLOAD_LDS16(ga, la);
            GLOAD_LDS16(gb, lb);
        }
        __syncthreads();

        // ---- compute: 2 k-steps of 32, 4x4 MFMA tiles per wave
        #pragma unroll
        for (int ko = 0; ko < 2; ++ko) {
            bf16x8 af[4], bfr[4];
            #pragma unroll
            for (int t = 0; t < 4; ++t) {
                int rm = wm + t * 16 + l15;
                int ca = (ko * 4 + quad) ^ (rm & 7);
                af[t] = *(const bf16x8*)(As + rm * 64 + ca * 8);
                int rn = wn + t * 16 + l15;
                int cb = (ko * 4 + quad) ^ (rn & 7);
                bfr[t] = *(const bf16x8*)(Bs + rn * 64 + cb * 8);
            }
            #pragma unroll
            for (int mt = 0; mt < 4; ++mt)
                #pragma unroll
                for (int nt = 0; nt < 4; ++nt)
                    acc[mt][nt] = __builtin_amdgcn_mfma_f32_16x16x32_bf16(
                        af[mt], bfr[nt], acc[mt][nt], 0, 0, 0);
        }
        __syncthreads();
    }

    // ---- epilogue: C/D layout col = lane&15, row = (lane>>4)*4 + r
    #pragma unroll
    for (int mt = 0; mt < 4; ++mt) {
        #pragma unroll
        for (int nt = 0; nt < 4; ++nt) {
            int n = n0 + wn + nt * 16 + l15;
            float bv = bias[n];
            #pragma unroll
            for (int r = 0; r < 4; ++r) {
                int m = m0 + wm + mt * 16 + quad * 4 + r;
                float v = acc[mt][nt][r] + bv;
                if (EPI == 0) {
                    v = 0.5f * v * (1.0f + erff(v * 0.70710678118654752f));
                    ((__bf16*)Cout)[(size_t)m * N + n] = (__bf16)v;
                } else {
                    ((float*)Cout)[(size_t)m * N + n] = v;
                }
            }
        }
    }
}

extern "C" void kernel_launch(void* const* d_in, const int* in_sizes, int n_in,
                              void* d_out, int out_size, void* d_ws, size_t ws_size,
                              hipStream_t stream) {
    const float* x  = (const float*)d_in[0];
    const float* w1 = (const float*)d_in[1];
    const float* b1 = (const float*)d_in[2];
    const float* w2 = (const float*)d_in[3];
    const float* b2 = (const float*)d_in[4];
    float* out = (float*)d_out;

    // workspace layout (bytes):
    //   [0,8)        : sum|w1|, sum|w2|
    //   256          : xb   bf16 [16384, 2048]   64 MiB
    //   +64Mi        : w1q  bf16 [ 8192, 2048]   32 MiB
    //   +32Mi        : w2q  bf16 [ 2048, 8192]   32 MiB
    //   +32Mi        : h    bf16 [16384, 8192]  256 MiB
    char* ws = (char*)d_ws;
    float* sums = (float*)ws;
    __bf16* xb  = (__bf16*)(ws + 256);
    __bf16* w1q = xb  + (size_t)MTOK * D_MODEL;
    __bf16* w2q = w1q + (size_t)D_FF * D_MODEL;
    __bf16* h   = w2q + (size_t)D_MODEL * D_FF;

    hipMemsetAsync(sums, 0, 2 * sizeof(float), stream);

    const int NW = D_FF * D_MODEL;  // 16,777,216 (both weights)
    absum_kernel<<<1024, 256, 0, stream>>>(w1, NW / 4, sums + 0);
    absum_kernel<<<1024, 256, 0, stream>>>(w2, NW / 4, sums + 1);

    quant_kernel<<<NW / 4 / 256, 256, 0, stream>>>(w1, NW, sums + 0, 1.0f / NW, w1q);
    quant_kernel<<<NW / 4 / 256, 256, 0, stream>>>(w2, NW, sums + 1, 1.0f / NW, w2q);

    const int NX = MTOK * D_MODEL;  // 33,554,432
    cvt_kernel<<<NX / 4 / 256, 256, 0, stream>>>(x, xb, NX);

    dim3 g1(D_FF / 128, MTOK / 128);     // (64, 128)
    gemm_bt<0><<<g1, 256, 0, stream>>>(xb, w1q, b1, (void*)h, MTOK, D_FF, D_MODEL);

    dim3 g2(D_MODEL / 128, MTOK / 128);  // (16, 128)
    gemm_bt<1><<<g2, 256, 0, stream>>>(h, w2q, b2, (void*)out, MTOK, D_MODEL, D_FF);
}

// Round 2
// 1493.179 us; speedup vs baseline: 1.0831x; 1.0831x over previous
//
#include <hip/hip_runtime.h>
#include <hip/hip_bf16.h>
#include <math.h>
#include <stdint.h>

#define D_MODEL 2048
#define D_FF    8192
#define MTOK    16384   // 4 * 4096 tokens
#define NW      (D_FF * D_MODEL)   // elements per weight matrix

typedef __bf16 bf16x8 __attribute__((ext_vector_type(8)));
typedef float  f32x16 __attribute__((ext_vector_type(16)));

// width-16 async global->LDS (per-lane global addr, wave-uniform LDS base + lane*16)
#define GLOAD_LDS16(gp, lp)                                                   \
  __builtin_amdgcn_global_load_lds(                                           \
      (__attribute__((address_space(1))) void*)(gp),                          \
      (__attribute__((address_space(3))) void*)(lp), 16, 0, 0)

// ---------------- stage 1: deterministic double partial sums of |w| ----------------
// grid (1024, 2): y selects weight. Per-thread sequential double accumulation,
// fixed-order LDS tree -> bitwise-deterministic across runs (no atomics).
__global__ void absum_s1(const float* __restrict__ w1, const float* __restrict__ w2,
                         double* __restrict__ partials) {
    const float* w = blockIdx.y ? w2 : w1;
    __shared__ double sm[256];
    int tid = blockIdx.x * 256 + threadIdx.x;
    double s = 0.0;
    for (int i = tid; i < NW / 4; i += 1024 * 256) {
        float4 v = ((const float4*)w)[i];
        s += (double)fabsf(v.x) + (double)fabsf(v.y) + (double)fabsf(v.z) + (double)fabsf(v.w);
    }
    sm[threadIdx.x] = s;
    __syncthreads();
    for (int off = 128; off > 0; off >>= 1) {
        if (threadIdx.x < off) sm[threadIdx.x] += sm[threadIdx.x + off];
        __syncthreads();
    }
    if (threadIdx.x == 0) partials[blockIdx.y * 1024 + blockIdx.x] = sm[0];
}

// ---------------- stage 2: 1024 partials -> float threshold 0.7*mean ----------------
__global__ void absum_s2(const double* __restrict__ partials, float* __restrict__ thr) {
    __shared__ double sm[256];
    for (int wsel = 0; wsel < 2; ++wsel) {
        const double* p = partials + wsel * 1024;
        double s = p[threadIdx.x] + p[threadIdx.x + 256] + p[threadIdx.x + 512] + p[threadIdx.x + 768];
        sm[threadIdx.x] = s;
        __syncthreads();
        for (int off = 128; off > 0; off >>= 1) {
            if (threadIdx.x < off) sm[threadIdx.x] += sm[threadIdx.x + off];
            __syncthreads();
        }
        if (threadIdx.x == 0) thr[wsel] = (float)(0.7 * (sm[0] / (double)NW));
        __syncthreads();
    }
}

// ---------------- ternarize both weights to bf16 {-1,0,+1}, fused ----------------
__global__ void quant2(const float* __restrict__ w1, const float* __restrict__ w2,
                       const float* __restrict__ thr,
                       __bf16* __restrict__ q1, __bf16* __restrict__ q2) {
    const float* w = blockIdx.y ? w2 : w1;
    __bf16* q = blockIdx.y ? q2 : q1;
    float t = thr[blockIdx.y];
    int i = (blockIdx.x * 256 + threadIdx.x) * 4;
    float4 v = *(const float4*)(w + i);
    __bf16 o0 = (__bf16)((fabsf(v.x) >= t) ? (v.x > 0.f ? 1.f : -1.f) : 0.f);
    __bf16 o1 = (__bf16)((fabsf(v.y) >= t) ? (v.y > 0.f ? 1.f : -1.f) : 0.f);
    __bf16 o2 = (__bf16)((fabsf(v.z) >= t) ? (v.z > 0.f ? 1.f : -1.f) : 0.f);
    __bf16 o3 = (__bf16)((fabsf(v.w) >= t) ? (v.w > 0.f ? 1.f : -1.f) : 0.f);
    q[i] = o0; q[i + 1] = o1; q[i + 2] = o2; q[i + 3] = o3;
}

// ---------------- x fp32 -> bf16 ----------------
__global__ void cvt_kernel(const float* __restrict__ x, __bf16* __restrict__ xb, int n) {
    int i = (blockIdx.x * blockDim.x + threadIdx.x) * 4;
    if (i >= n) return;
    float4 v = *(const float4*)(x + i);
    xb[i] = (__bf16)v.x; xb[i + 1] = (__bf16)v.y; xb[i + 2] = (__bf16)v.z; xb[i + 3] = (__bf16)v.w;
}

// ---------------- 128x128 bf16 MFMA GEMM (32x32x16), C = A[M,K] * B[N,K]^T ----------
// EPI==0: out = bf16( gelu_exact(C + bias) )   (fc1)
// EPI==1: out = f32 ( C + bias )               (fc2)
// LDS tiles [128 rows][64 k] bf16; 16B chunk c of a row stored at slot c^(row&7).
// Under 16-lane b128 phasing this makes both staging and fragment reads 2-way
// (free) bank aliases — R1 measured SQ_LDS_BANK_CONFLICT == 0 with this scheme.
template<int EPI>
__global__ __launch_bounds__(256) void gemm_bt(
    const __bf16* __restrict__ A,   // [M,K]
    const __bf16* __restrict__ B,   // [N,K]
    const float*  __restrict__ bias,// [N]
    void* __restrict__ Cout,
    int M, int N, int K)
{
    __shared__ __bf16 As[128 * 64];
    __shared__ __bf16 Bs[128 * 64];

    const int tid  = threadIdx.x;
    const int wave = tid >> 6;
    const int lane = tid & 63;
    const int m0 = blockIdx.y * 128;
    const int n0 = blockIdx.x * 128;
    const int wm = (wave >> 1) * 64;   // wave's m offset in tile
    const int wn = (wave & 1) * 64;    // wave's n offset in tile
    const int l31 = lane & 31;
    const int h1  = lane >> 5;

    f32x16 acc[2][2] = {};

    // ---- strength-reduced staging pointers (advance by 64 bf16 per kt)
    const __bf16* gA[4]; const __bf16* gB[4];
    char* lA[4]; char* lB[4];
    #pragma unroll
    for (int it = 0; it < 4; ++it) {
        int slot = it * 256 + wave * 64 + lane;      // LDS 16B-slot index
        int row  = slot >> 3;
        int cg   = (slot & 7) ^ (row & 7);           // global 16B chunk in row (un-swizzle)
        gA[it] = A + (size_t)(m0 + row) * K + cg * 8;
        gB[it] = B + (size_t)(n0 + row) * K + cg * 8;
        lA[it] = (char*)As + (size_t)(it * 256 + wave * 64) * 16; // wave-uniform base
        lB[it] = (char*)Bs + (size_t)(it * 256 + wave * 64) * 16;
    }

    const int nk = K >> 6;
    for (int kt = 0; kt < nk; ++kt) {
        #pragma unroll
        for (int it = 0; it < 4; ++it) {
            GLOAD_LDS16(gA[it], lA[it]);
            GLOAD_LDS16(gB[it], lB[it]);
            gA[it] += 64; gB[it] += 64;
        }
        __syncthreads();

        // ---- compute: 4 k-steps of 16; per wave 2x2 tiles of 32x32
        // A frag: m = lane&31, k = ko*16 + (lane>>5)*8 + j  (by symmetry with
        // the R1-verified 16x16x32 layout m=lane&15, k = 8*(lane>>4)+j)
        #pragma unroll
        for (int ko = 0; ko < 4; ++ko) {
            bf16x8 af[2], bfr[2];
            #pragma unroll
            for (int t = 0; t < 2; ++t) {
                int rm = wm + t * 32 + l31;
                int ca = (ko * 2 + h1) ^ (rm & 7);
                af[t] = *(const bf16x8*)(As + rm * 64 + ca * 8);
                int rn = wn + t * 32 + l31;
                int cb = (ko * 2 + h1) ^ (rn & 7);
                bfr[t] = *(const bf16x8*)(Bs + rn * 64 + cb * 8);
            }
            #pragma unroll
            for (int mt = 0; mt < 2; ++mt)
                #pragma unroll
                for (int nt = 0; nt < 2; ++nt)
                    acc[mt][nt] = __builtin_amdgcn_mfma_f32_32x32x16_bf16(
                        af[mt], bfr[nt], acc[mt][nt], 0, 0, 0);
        }
        __syncthreads();
    }

    // ---- epilogue: 32x32 C/D layout: col(n)=lane&31, row(m)=(r&3)+8*(r>>2)+4*(lane>>5)
    #pragma unroll
    for (int mt = 0; mt < 2; ++mt) {
        #pragma unroll
        for (int nt = 0; nt < 2; ++nt) {
            int n = n0 + wn + nt * 32 + l31;
            float bv = bias[n];
            #pragma unroll
            for (int r = 0; r < 16; ++r) {
                int m = m0 + wm + mt * 32 + (r & 3) + 8 * (r >> 2) + 4 * h1;
                float v = acc[mt][nt][r] + bv;
                if (EPI == 0) {
                    v = 0.5f * v * (1.0f + erff(v * 0.70710678118654752f));
                    ((__bf16*)Cout)[(size_t)m * N + n] = (__bf16)v;
                } else {
                    ((float*)Cout)[(size_t)m * N + n] = v;
                }
            }
        }
    }
}

extern "C" void kernel_launch(void* const* d_in, const int* in_sizes, int n_in,
                              void* d_out, int out_size, void* d_ws, size_t ws_size,
                              hipStream_t stream) {
    const float* x  = (const float*)d_in[0];
    const float* w1 = (const float*)d_in[1];
    const float* b1 = (const float*)d_in[2];
    const float* w2 = (const float*)d_in[3];
    const float* b2 = (const float*)d_in[4];
    float* out = (float*)d_out;

    // workspace layout (bytes):
    //   [0,8)   : thr[2] (float)
    //   256     : xb   bf16 [16384, 2048]   64 MiB
    //   +64Mi   : w1q  bf16 [ 8192, 2048]   32 MiB
    //   +32Mi   : w2q  bf16 [ 2048, 8192]   32 MiB
    //   +32Mi   : h    bf16 [16384, 8192]  256 MiB  (partials alias h: used before fc1)
    char* ws = (char*)d_ws;
    float* thr = (float*)ws;
    __bf16* xb  = (__bf16*)(ws + 256);
    __bf16* w1q = xb  + (size_t)MTOK * D_MODEL;
    __bf16* w2q = w1q + (size_t)D_FF * D_MODEL;
    __bf16* h   = w2q + (size_t)D_MODEL * D_FF;
    double* partials = (double*)h;   // 2048 doubles, consumed before h is written

    absum_s1<<<dim3(1024, 2), 256, 0, stream>>>(w1, w2, partials);
    absum_s2<<<1, 256, 0, stream>>>(partials, thr);

    __bf16* w1q_ = w1q; __bf16* w2q_ = w2q;
    quant2<<<dim3(NW / 4 / 256, 2), 256, 0, stream>>>(w1, w2, thr, w1q_, w2q_);

    const int NX = MTOK * D_MODEL;  // 33,554,432
    cvt_kernel<<<NX / 4 / 256, 256, 0, stream>>>(x, xb, NX);

    dim3 g1(D_FF / 128, MTOK / 128);     // (64, 128)
    gemm_bt<0><<<g1, 256, 0, stream>>>(xb, w1q, b1, (void*)h, MTOK, D_FF, D_MODEL);

    dim3 g2(D_MODEL / 128, MTOK / 128);  // (16, 128)
    gemm_bt<1><<<g2, 256, 0, stream>>>(h, w2q, b2, (void*)out, MTOK, D_MODEL, D_FF);
}

// Round 3
// 1167.618 us; speedup vs baseline: 1.3850x; 1.2788x over previous
//
#include <hip/hip_runtime.h>
#include <hip/hip_bf16.h>
#include <math.h>
#include <stdint.h>

#define D_MODEL 2048
#define D_FF    8192
#define MTOK    16384   // 4 * 4096 tokens
#define NW      (D_FF * D_MODEL)   // elements per weight matrix

typedef int    i32x4  __attribute__((ext_vector_type(4)));
typedef __bf16 bf16x8 __attribute__((ext_vector_type(8)));

// width-16 async global->LDS (per-lane global addr, wave-uniform LDS base + lane*16)
#define GLOAD_LDS16(gp, lp)                                                   \
  __builtin_amdgcn_global_load_lds(                                           \
      (__attribute__((address_space(1))) void*)(gp),                          \
      (__attribute__((address_space(3))) void*)(lp), 16, 0, 0)

// ---------------- stage 1: deterministic double partial sums of |w| ----------------
__global__ void absum_s1(const float* __restrict__ w1, const float* __restrict__ w2,
                         double* __restrict__ partials) {
    const float* w = blockIdx.y ? w2 : w1;
    __shared__ double sm[256];
    int tid = blockIdx.x * 256 + threadIdx.x;
    double s = 0.0;
    for (int i = tid; i < NW / 4; i += 1024 * 256) {
        float4 v = ((const float4*)w)[i];
        s += (double)fabsf(v.x) + (double)fabsf(v.y) + (double)fabsf(v.z) + (double)fabsf(v.w);
    }
    sm[threadIdx.x] = s;
    __syncthreads();
    for (int off = 128; off > 0; off >>= 1) {
        if (threadIdx.x < off) sm[threadIdx.x] += sm[threadIdx.x + off];
        __syncthreads();
    }
    if (threadIdx.x == 0) partials[blockIdx.y * 1024 + blockIdx.x] = sm[0];
}

// ---------------- stage 2: 1024 partials -> float threshold 0.7*mean ----------------
__global__ void absum_s2(const double* __restrict__ partials, float* __restrict__ thr) {
    __shared__ double sm[256];
    for (int wsel = 0; wsel < 2; ++wsel) {
        const double* p = partials + wsel * 1024;
        double s = p[threadIdx.x] + p[threadIdx.x + 256] + p[threadIdx.x + 512] + p[threadIdx.x + 768];
        sm[threadIdx.x] = s;
        __syncthreads();
        for (int off = 128; off > 0; off >>= 1) {
            if (threadIdx.x < off) sm[threadIdx.x] += sm[threadIdx.x + off];
            __syncthreads();
        }
        if (threadIdx.x == 0) thr[wsel] = (float)(0.7 * (sm[0] / (double)NW));
        __syncthreads();
    }
}

// ---------------- w1 -> ternary i8, elementwise ----------------
__global__ void quantw1(const float* __restrict__ w, const float* __restrict__ thr,
                        int8_t* __restrict__ q) {
    float t = thr[0];
    int i = (blockIdx.x * 256 + threadIdx.x) * 4;
    float4 v = *(const float4*)(w + i);
    char4 o;
    o.x = (fabsf(v.x) >= t) ? (v.x > 0.f ? 1 : -1) : 0;
    o.y = (fabsf(v.y) >= t) ? (v.y > 0.f ? 1 : -1) : 0;
    o.z = (fabsf(v.z) >= t) ? (v.z > 0.f ? 1 : -1) : 0;
    o.w = (fabsf(v.w) >= t) ? (v.w > 0.f ? 1 : -1) : 0;
    *(char4*)(q + i) = o;
}

// ---------------- w2 -> ternary i8, one block per row, + row sums (colsum) ---------
__global__ void quantw2(const float* __restrict__ w, const float* __restrict__ thr,
                        int8_t* __restrict__ q, float* __restrict__ colsum) {
    __shared__ int sm[256];
    float t = thr[1];
    const int row = blockIdx.x;
    const int tid = threadIdx.x;
    int isum = 0;
    #pragma unroll
    for (int j = 0; j < 8; ++j) {
        int idx = row * D_FF + j * 1024 + tid * 4;
        float4 v = *(const float4*)(w + idx);
        char4 o;
        o.x = (fabsf(v.x) >= t) ? (v.x > 0.f ? 1 : -1) : 0;
        o.y = (fabsf(v.y) >= t) ? (v.y > 0.f ? 1 : -1) : 0;
        o.z = (fabsf(v.z) >= t) ? (v.z > 0.f ? 1 : -1) : 0;
        o.w = (fabsf(v.w) >= t) ? (v.w > 0.f ? 1 : -1) : 0;
        isum += o.x + o.y + o.z + o.w;
        *(char4*)(q + idx) = o;
    }
    sm[tid] = isum;
    __syncthreads();
    for (int off = 128; off > 0; off >>= 1) {
        if (tid < off) sm[tid] += sm[tid + off];
        __syncthreads();
    }
    if (tid == 0) colsum[row] = (float)sm[0];
}

// ---------------- x -> per-row symmetric i8, one block per token row ----------------
__global__ void xquant(const float* __restrict__ x, int8_t* __restrict__ xq,
                       float* __restrict__ sx) {
    __shared__ float sm[256];
    const int row = blockIdx.x;
    const int tid = threadIdx.x;
    float4 v[2];
    float mx = 0.f;
    #pragma unroll
    for (int j = 0; j < 2; ++j) {
        v[j] = *(const float4*)(x + (size_t)row * D_MODEL + j * 1024 + tid * 4);
        mx = fmaxf(mx, fmaxf(fmaxf(fabsf(v[j].x), fabsf(v[j].y)),
                             fmaxf(fabsf(v[j].z), fabsf(v[j].w))));
    }
    sm[tid] = mx;
    __syncthreads();
    for (int off = 128; off > 0; off >>= 1) {
        if (tid < off) sm[tid] = fmaxf(sm[tid], sm[tid + off]);
        __syncthreads();
    }
    float m = sm[0];
    float inv = (m > 0.f) ? 127.f / m : 0.f;
    if (tid == 0) sx[row] = (m > 0.f) ? m / 127.f : 0.f;
    #pragma unroll
    for (int j = 0; j < 2; ++j) {
        char4 o;
        o.x = (int8_t)min(127, max(-127, __float2int_rn(v[j].x * inv)));
        o.y = (int8_t)min(127, max(-127, __float2int_rn(v[j].y * inv)));
        o.z = (int8_t)min(127, max(-127, __float2int_rn(v[j].z * inv)));
        o.w = (int8_t)min(127, max(-127, __float2int_rn(v[j].w * inv)));
        *(char4*)(xq + (size_t)row * D_MODEL + j * 1024 + tid * 4) = o;
    }
}

// ---------------- gelu(h) bf16 -> per-row ASYMMETRIC i8 (zero-point via colsum) -----
// g ~= s*qs + o with o = 127*s + gmin, gmin = -0.17 (gelu lower bound).
__global__ void hquant(const __bf16* __restrict__ h, int8_t* __restrict__ hq,
                       float2* __restrict__ sh) {
    __shared__ float sm[256];
    const int row = blockIdx.x;
    const int tid = threadIdx.x;
    const float gmin = -0.17f;
    float vals[4][8];
    float mx = -1e30f;
    #pragma unroll
    for (int j = 0; j < 4; ++j) {
        bf16x8 b = *(const bf16x8*)(h + (size_t)row * D_FF + j * 2048 + tid * 8);
        #pragma unroll
        for (int e = 0; e < 8; ++e) {
            float f = (float)b[e];
            vals[j][e] = f;
            mx = fmaxf(mx, f);
        }
    }
    sm[tid] = mx;
    __syncthreads();
    for (int off = 128; off > 0; off >>= 1) {
        if (tid < off) sm[tid] = fmaxf(sm[tid], sm[tid + off]);
        __syncthreads();
    }
    float M = sm[0];
    float s = (M - gmin) / 254.f;
    float inv = 254.f / (M - gmin);   // M >= ~0 in practice; M-gmin >= 0.17-ish > 0
    if (tid == 0) sh[row] = make_float2(s, 127.f * s + gmin);
    #pragma unroll
    for (int j = 0; j < 4; ++j) {
        char4 o0, o1;
        int q[8];
        #pragma unroll
        for (int e = 0; e < 8; ++e)
            q[e] = min(127, max(-127, __float2int_rn((vals[j][e] - gmin) * inv) - 127));
        o0.x = q[0]; o0.y = q[1]; o0.z = q[2]; o0.w = q[3];
        o1.x = q[4]; o1.y = q[5]; o1.z = q[6]; o1.w = q[7];
        int8_t* p = hq + (size_t)row * D_FF + j * 2048 + tid * 8;
        *(char4*)p = o0;
        *(char4*)(p + 4) = o1;
    }
}

// ---------------- 128x128 i8 MFMA GEMM (16x16x64, BK=128), C = A[M,K] * B[N,K]^T ----
// EPI==0 (fc1): h[m,n] = bf16( gelu( rs[m] * acc + bias[n] ) )
// EPI==1 (fc2): out[m,n] = f32( rs2[m].x * acc + rs2[m].y * colsum[n] + bias[n] )
// LDS tiles [128 rows][128 i8] = 16 KiB each; 16B chunk c of a row stored at slot
// c^(row&7). Byte pattern identical to R1's bf16 kernel which measured
// SQ_LDS_BANK_CONFLICT == 0 (rows repeat per 16-lane group in frag reads).
template<int EPI>
__global__ __launch_bounds__(256) void gemm_i8(
    const int8_t* __restrict__ A,    // [M,K]
    const int8_t* __restrict__ B,    // [N,K]
    const float*  __restrict__ bias, // [N]
    const float*  __restrict__ rs,   // fc1: sx[M] ; fc2: (float2*)sh[M]
    const float*  __restrict__ colsum, // fc2 only: [N]
    void* __restrict__ Cout,
    int M, int N, int K)
{
    __shared__ int8_t As[128 * 128];
    __shared__ int8_t Bs[128 * 128];

    const int tid  = threadIdx.x;
    const int wave = tid >> 6;
    const int lane = tid & 63;
    const int m0 = blockIdx.y * 128;
    const int n0 = blockIdx.x * 128;
    const int wm = (wave >> 1) * 64;
    const int wn = (wave & 1) * 64;
    const int quad = lane >> 4;
    const int l15  = lane & 15;

    i32x4 acc[4][4] = {};

    // staging pointers: 1024 16B chunks per tile, 4 per thread per tile
    const int8_t* gA[4]; const int8_t* gB[4];
    char* lA[4]; char* lB[4];
    #pragma unroll
    for (int it = 0; it < 4; ++it) {
        int slot = it * 256 + tid;          // [0,1024)
        int row  = slot >> 3;               // [0,128)
        int cg   = (slot & 7) ^ (row & 7);  // global 16B chunk in row (un-swizzle)
        gA[it] = A + (size_t)(m0 + row) * K + cg * 16;
        gB[it] = B + (size_t)(n0 + row) * K + cg * 16;
        lA[it] = (char*)As + (size_t)(it * 256 + wave * 64) * 16;
        lB[it] = (char*)Bs + (size_t)(it * 256 + wave * 64) * 16;
    }

    const int nk = K >> 7;
    for (int kt = 0; kt < nk; ++kt) {
        #pragma unroll
        for (int it = 0; it < 4; ++it) {
            GLOAD_LDS16(gA[it], lA[it]);
            GLOAD_LDS16(gB[it], lB[it]);
            gA[it] += 128; gB[it] += 128;
        }
        __syncthreads();

        // 2 k-steps of 64; per wave 4x4 tiles of 16x16
        // A frag: m = lane&15, k = ko*64 + quad*16 + j  -> 16B chunk = ko*4+quad
        #pragma unroll
        for (int ko = 0; ko < 2; ++ko) {
            i32x4 af[4], bfr[4];
            #pragma unroll
            for (int t = 0; t < 4; ++t) {
                int rm = wm + t * 16 + l15;
                int ca = (ko * 4 + quad) ^ (rm & 7);
                af[t] = *(const i32x4*)(As + rm * 128 + ca * 16);
                int rn = wn + t * 16 + l15;
                int cb = (ko * 4 + quad) ^ (rn & 7);
                bfr[t] = *(const i32x4*)(Bs + rn * 128 + cb * 16);
            }
            #pragma unroll
            for (int mt = 0; mt < 4; ++mt)
                #pragma unroll
                for (int nt = 0; nt < 4; ++nt)
                    acc[mt][nt] = __builtin_amdgcn_mfma_i32_16x16x64_i8(
                        af[mt], bfr[nt], acc[mt][nt], 0, 0, 0);
        }
        __syncthreads();
    }

    // epilogue: C/D layout col = lane&15, row = quad*4 + r (dtype-independent)
    #pragma unroll
    for (int mt = 0; mt < 4; ++mt) {
        #pragma unroll
        for (int nt = 0; nt < 4; ++nt) {
            int n = n0 + wn + nt * 16 + l15;
            float bv = bias[n];
            float cs = (EPI == 1) ? colsum[n] : 0.f;
            #pragma unroll
            for (int r = 0; r < 4; ++r) {
                int m = m0 + wm + mt * 16 + quad * 4 + r;
                float a = (float)acc[mt][nt][r];
                if (EPI == 0) {
                    float v = rs[m] * a + bv;
                    v = 0.5f * v * (1.0f + erff(v * 0.70710678118654752f));
                    ((__bf16*)Cout)[(size_t)m * N + n] = (__bf16)v;
                } else {
                    float2 so = ((const float2*)rs)[m];
                    ((float*)Cout)[(size_t)m * N + n] = so.x * a + so.y * cs + bv;
                }
            }
        }
    }
}

extern "C" void kernel_launch(void* const* d_in, const int* in_sizes, int n_in,
                              void* d_out, int out_size, void* d_ws, size_t ws_size,
                              hipStream_t stream) {
    const float* x  = (const float*)d_in[0];
    const float* w1 = (const float*)d_in[1];
    const float* b1 = (const float*)d_in[2];
    const float* w2 = (const float*)d_in[3];
    const float* b2 = (const float*)d_in[4];
    float* out = (float*)d_out;

    // workspace layout (bytes):
    //   0       : thr[2] float                  (pad to 256)
    //   256     : sx     float [16384]           64 KiB
    //   +64Ki   : sh     float2[16384]          128 KiB
    //   +128Ki  : colsum float [2048]             8 KiB (pad to 64 KiB)
    //   256Ki+256: xq    i8 [16384,2048]         32 MiB
    //   next    : w1q    i8 [ 8192,2048]         16 MiB
    //   next    : w2q    i8 [ 2048,8192]         16 MiB
    //   next    : hq     i8 [16384,8192]        128 MiB
    //   next    : h      bf16 [16384,8192]      256 MiB (absum partials alias h)
    char* ws = (char*)d_ws;
    float*  thr = (float*)ws;
    float*  sx  = (float*)(ws + 256);
    float2* sh  = (float2*)(ws + 256 + (64 << 10));
    float*  colsum = (float*)(ws + 256 + (192 << 10));
    int8_t* xq  = (int8_t*)(ws + 256 + (256 << 10));
    int8_t* w1q = xq  + (size_t)MTOK * D_MODEL;
    int8_t* w2q = w1q + (size_t)D_FF * D_MODEL;
    int8_t* hq  = w2q + (size_t)D_MODEL * D_FF;
    __bf16* h   = (__bf16*)(hq + (size_t)MTOK * D_FF);
    double* partials = (double*)h;   // 16 KiB, consumed before h is written

    absum_s1<<<dim3(1024, 2), 256, 0, stream>>>(w1, w2, partials);
    absum_s2<<<1, 256, 0, stream>>>(partials, thr);

    quantw1<<<NW / 1024, 256, 0, stream>>>(w1, thr, w1q);
    quantw2<<<D_MODEL, 256, 0, stream>>>(w2, thr, w2q, colsum);
    xquant<<<MTOK, 256, 0, stream>>>(x, xq, sx);

    dim3 g1(D_FF / 128, MTOK / 128);     // (64, 128)
    gemm_i8<0><<<g1, 256, 0, stream>>>(xq, w1q, b1, sx, nullptr, (void*)h,
                                       MTOK, D_FF, D_MODEL);

    hquant<<<MTOK, 256, 0, stream>>>(h, hq, sh);

    dim3 g2(D_MODEL / 128, MTOK / 128);  // (16, 128)
    gemm_i8<1><<<g2, 256, 0, stream>>>(hq, w2q, b2, (const float*)sh, colsum, (void*)out,
                                       MTOK, D_MODEL, D_FF);
}